// Round 10
// baseline (368.388 us; speedup 1.0000x reference)
//
#include <hip/hip_runtime.h>

// VQ-VAE vector quantizer, MI355X — MFMA screen (frag-major, global_load_lds,
// counted-vmcnt pipeline) + exact-chain refine.
// z: (4,256,16,32,32) f32 ; emb: (1024,256) f32
// out (f32): z_q_st[16777216] | vq_loss | perplexity | indices[65536]
//
// Exactness contract (validated rounds 2-9, absmax 0):
//   x_sq[n], e_sq[k]: numpy pairwise sum of fl32(v*v) (two 128-blocks, 8 accs)
//   xe[n][k]: single sequential f32 FMA chain over c=0..255
//   d = fl32( fl32(x_sq+e_sq) - 2*xe ), argmin first-min tie-break.
// Screen = bf16-split MFMA (zh*eh + zl*eh + zh*el); rows with merged
// (min2-min1) <= T_GAP=4e-4 (>> analytic screen-error bound ~7e-5) are
// recomputed by the bit-exact scalar chain (refine).
//
// Round-10: r6/r8/r9 all pinned at 208-240us regardless of LDS structure ->
// the per-step stage->vmcnt(0)->__syncthreads drain is the critical path
// (m233: 2-phase stall ~72%). Now: global_load_lds DMA straight into the
// frag-major chunks (wave-uniform base + lane*16 == our layout), triple
// buffer, counted s_waitcnt vmcnt(6) + RAW s_barrier (never drain in-loop),
// prefetch depth 2, setprio around the MFMA cluster. No ds_writes at all.

#define C_DIM 256
#define K_CODES 1024
#define N_VEC 65536
#define T_GAP 4e-4f

#define OUT_ZQ_SIZE 16777216
#define OUT_LOSS_OFF 16777216
#define OUT_PP_OFF   16777217
#define OUT_IDX_OFF  16777218

// ws layout (bytes)
#define WS_EH    0          // bf16 frag-major [32 kt][16 q][64 l][8]   512 KB
#define WS_EL    524288     // same                                     512 KB
#define WS_ESQ   1048576    // f32 [1024]
#define WS_XSQ   1052672    // f32 [65536]
#define WS_CNT   1314816    // u32 counts[1024]
#define WS_LOSS  1318912    // f64 loss
#define WS_FLC   1318920    // u32 flag count
#define WS_SIDX  1318928    // i32 screen_idx[65536]
#define WS_FLIST 1581072    // u32 flag_list[65536]
#define WS_PM1   1843264    // f32 [4][65536]
#define WS_EMBT  1843264    // f32 [256][1024] (overlays PM1 after merge)
#define WS_PM2   2891840    // f32 [4][65536]
#define WS_PIX   3940416    // u16 [4][65536]  (ends 4464704)

typedef __attribute__((ext_vector_type(8))) short short8;
typedef __attribute__((ext_vector_type(8))) unsigned short ushort8;
typedef __attribute__((ext_vector_type(16))) float f32x16;

__device__ __forceinline__ unsigned short bf16_rne(float v) {
    unsigned u = __float_as_uint(v);
    unsigned r = (u + 0x7FFFu + ((u >> 16) & 1u)) >> 16;
    return (unsigned short)r;
}

// fragment-major address (in shorts) of element (row, c) within a panel:
//   tile = row>>5, q = c>>4, lane = (row&31) + 32*((c>>3)&1), j = c&7
//   off  = tile*8192 + q*512 + lane*8 + j

// ---------- conversions ----------

__global__ __launch_bounds__(256) void convert_z_kernel(const float* __restrict__ z,
                                                        unsigned short* __restrict__ zhF,
                                                        unsigned short* __restrict__ zlF) {
    const int tid = threadIdx.x;
    const int ln = tid & 63;
    const int og = tid >> 6;
    const int n0 = blockIdx.x * 64;
    const int b = n0 >> 14, s0 = n0 & 16383;
    const int n = n0 + ln;
    const size_t zbase = ((size_t)b << 22) + s0 + ln;
    const size_t tbase = (size_t)(n >> 5) * 8192;
    const int lr = n & 31;
#pragma unroll
    for (int t = 0; t < 8; ++t) {
        int o = og + t * 4;        // c-octet 0..31
        int c0 = o * 8;
        ushort8 hb, lb;
#pragma unroll
        for (int j = 0; j < 8; ++j) {
            float v = z[zbase + ((size_t)(c0 + j) << 14)];
            unsigned short h = bf16_rne(v);
            hb[j] = h;
            lb[j] = bf16_rne(v - __uint_as_float((unsigned)h << 16));
        }
        size_t off = tbase + (size_t)(o >> 1) * 512 + (size_t)(lr + 32 * (o & 1)) * 8;
        *reinterpret_cast<ushort8*>(zhF + off) = hb;
        *reinterpret_cast<ushort8*>(zlF + off) = lb;
    }
}

__global__ __launch_bounds__(256) void convert_e_kernel(const float* __restrict__ emb,
                                                        unsigned short* __restrict__ ehF,
                                                        unsigned short* __restrict__ elF) {
    int t = blockIdx.x * 256 + threadIdx.x;   // 32768 threads
    int k = t >> 5, o = t & 31;
    int c0 = o * 8;
    ushort8 hb, lb;
#pragma unroll
    for (int j = 0; j < 8; ++j) {
        float v = emb[k * C_DIM + c0 + j];
        unsigned short h = bf16_rne(v);
        hb[j] = h;
        lb[j] = bf16_rne(v - __uint_as_float((unsigned)h << 16));
    }
    size_t off = (size_t)(k >> 5) * 8192 + (size_t)(o >> 1) * 512 + (size_t)((k & 31) + 32 * (o & 1)) * 8;
    *reinterpret_cast<ushort8*>(ehF + off) = hb;
    *reinterpret_cast<ushort8*>(elF + off) = lb;
}

// ---------- exact norms (validated) ----------

__device__ __forceinline__ float pairwise_sq_128(const float* p) {
#pragma clang fp contract(off)
    float r[8];
#pragma unroll
    for (int j = 0; j < 8; ++j) { float v = p[j]; r[j] = v * v; }
#pragma unroll
    for (int i = 8; i < 128; i += 8)
#pragma unroll
        for (int j = 0; j < 8; ++j) { float v = p[i + j]; float t = v * v; r[j] = r[j] + t; }
    return ((r[0] + r[1]) + (r[2] + r[3])) + ((r[4] + r[5]) + (r[6] + r[7]));
}

__global__ __launch_bounds__(256) void esq_kernel(const float* __restrict__ emb,
                                                  float* __restrict__ esq) {
#pragma clang fp contract(off)
    __shared__ float tile[64 * 260];
    const int tid = threadIdx.x;
    const int k0 = blockIdx.x * 64;
#pragma unroll
    for (int r = 0; r < 64; ++r) {
        int idx = r * 256 + tid;
        tile[(idx >> 8) * 260 + (idx & 255)] = emb[k0 * C_DIM + idx];
    }
    __syncthreads();
    if (tid < 64) {
        const float* row = &tile[tid * 260];
        esq[k0 + tid] = pairwise_sq_128(row) + pairwise_sq_128(row + 128);
    }
}

__global__ __launch_bounds__(256) void xsq_kernel(const float* __restrict__ z,
                                                  float* __restrict__ xsq) {
#pragma clang fp contract(off)
    const int n = blockIdx.x * 256 + threadIdx.x;
    const int b = n >> 14, s = n & 16383;
    const float* base = z + ((size_t)b << 22) + s;
    float r[8], res;
#pragma unroll
    for (int j = 0; j < 8; ++j) { float v = base[(size_t)j << 14]; r[j] = v * v; }
#pragma unroll
    for (int i = 8; i < 128; i += 8)
#pragma unroll
        for (int j = 0; j < 8; ++j) { float v = base[(size_t)(i + j) << 14]; float t = v * v; r[j] = r[j] + t; }
    res = ((r[0] + r[1]) + (r[2] + r[3])) + ((r[4] + r[5]) + (r[6] + r[7]));
#pragma unroll
    for (int j = 0; j < 8; ++j) { float v = base[(size_t)(128 + j) << 14]; r[j] = v * v; }
#pragma unroll
    for (int i = 136; i < 256; i += 8)
#pragma unroll
        for (int j = 0; j < 8; ++j) { float v = base[(size_t)(i + j) << 14]; float t = v * v; r[j] = r[j] + t; }
    res = res + (((r[0] + r[1]) + (r[2] + r[3])) + ((r[4] + r[5]) + (r[6] + r[7])));
    xsq[n] = res;
}

__global__ __launch_bounds__(256) void transpose_kernel(const float* __restrict__ emb,
                                                        float* __restrict__ embT) {
    __shared__ float t[64][65];
    const int k0 = blockIdx.x * 64;
    const int c0 = blockIdx.y * 64;
    const int tx = threadIdx.x & 63, ty = threadIdx.x >> 6;
    for (int r = ty; r < 64; r += 4)
        t[r][tx] = emb[(k0 + r) * C_DIM + c0 + tx];
    __syncthreads();
    for (int r = ty; r < 64; r += 4)
        embT[(c0 + r) * K_CODES + k0 + tx] = t[tx][r];
}

// ---------- MFMA screen: frag-major, DMA-staged, counted-vmcnt pipeline ----------
// block 128n x 256k, wave 64n x 128k; 16 steps (one q per step), K = 3x16 q.

__global__ __launch_bounds__(256, 2) void screen_kernel(
    const unsigned short* __restrict__ zhF, const unsigned short* __restrict__ zlF,
    const unsigned short* __restrict__ ehF, const unsigned short* __restrict__ elF,
    const float* __restrict__ esq, const float* __restrict__ xsq,
    float* __restrict__ pm1, float* __restrict__ pm2,
    unsigned short* __restrict__ pix) {
    // 24 chunks/step (0-3 A_zh, 4-7 A_zl, 8-15 B_eh, 16-23 B_el), triple-buffered = 72 KB
    __shared__ __align__(16) unsigned short lbuf[3][24 * 512];
    __shared__ float lm1[2][128], lm2[2][128];
    __shared__ int   li1[2][128];

    const int tid = threadIdx.x;
    const int w = tid >> 6, l = tid & 63, lr = l & 31, lh = l >> 5;
    const int wn = w >> 1, wk = w & 1;
    const int bid = blockIdx.x;
    const int v = (bid & 7) * 256 + (bid >> 3);   // XCD-chunked bijective swizzle (2048 = 8*256)
    const int nb = v >> 2, kb = v & 3;
    const int n0 = nb * 128;
    const int k0 = kb * 256;
    const size_t atile0 = (size_t)(nb * 4) * 8192;   // shorts
    const size_t btile0 = (size_t)(kb * 8) * 8192;
    const int loff = l * 8;

    // per-wave DMA sources: chunks 6w .. 6w+5; global addr is per-lane (+loff),
    // LDS dest is wave-uniform chunk base (+lane*16 applied by HW).
    const unsigned short* gsrc[6];
#pragma unroll
    for (int ci = 0; ci < 6; ++ci) {
        int c = 6 * w + ci;
        const unsigned short* p;
        if (c < 4)       p = zhF + atile0 + (size_t)c * 8192;
        else if (c < 8)  p = zlF + atile0 + (size_t)(c - 4) * 8192;
        else if (c < 16) p = ehF + btile0 + (size_t)(c - 8) * 8192;
        else             p = elF + btile0 + (size_t)(c - 16) * 8192;
        gsrc[ci] = p + loff;
    }

#define STAGE(S) do {                                                               \
    const int _b = (S) % 3;                                                         \
    _Pragma("unroll")                                                               \
    for (int ci = 0; ci < 6; ++ci)                                                  \
        __builtin_amdgcn_global_load_lds(                                           \
            (const __attribute__((address_space(1))) void*)(gsrc[ci] + (S) * 512),  \
            (__attribute__((address_space(3))) void*)&lbuf[_b][(6 * w + ci) * 512], \
            16, 0, 0);                                                              \
} while (0)

    f32x16 acc[2][4];
#pragma unroll
    for (int i = 0; i < 2; ++i)
#pragma unroll
        for (int j = 0; j < 4; ++j)
#pragma unroll
            for (int r = 0; r < 16; ++r) acc[i][j][r] = 0.0f;

    STAGE(0);
    STAGE(1);

    for (int s = 0; s < 16; ++s) {
        const int cur = s % 3;
        // wait for OWN step-s chunks (6 remain in flight for s+1); raw barrier
        // publishes cross-wave completion without draining the s+1 prefetch.
        if (s == 15) { asm volatile("s_waitcnt vmcnt(0)" ::: "memory"); }
        else         { asm volatile("s_waitcnt vmcnt(6)" ::: "memory"); }
        __builtin_amdgcn_s_barrier();
        asm volatile("" ::: "memory");
        __builtin_amdgcn_sched_barrier(0);
        if (s < 14) STAGE(s + 2);   // buffer (s-1)%3 is free past the barrier

        short8 fah[2], fal[2], fbh[4], fbl[4];
#pragma unroll
        for (int i = 0; i < 2; ++i) {
            fah[i] = *reinterpret_cast<const short8*>(&lbuf[cur][(wn * 2 + i) * 512 + loff]);
            fal[i] = *reinterpret_cast<const short8*>(&lbuf[cur][(4 + wn * 2 + i) * 512 + loff]);
        }
#pragma unroll
        for (int j = 0; j < 4; ++j) {
            fbh[j] = *reinterpret_cast<const short8*>(&lbuf[cur][(8 + wk * 4 + j) * 512 + loff]);
            fbl[j] = *reinterpret_cast<const short8*>(&lbuf[cur][(16 + wk * 4 + j) * 512 + loff]);
        }
        __builtin_amdgcn_s_setprio(1);
#pragma unroll
        for (int i = 0; i < 2; ++i)
#pragma unroll
            for (int j = 0; j < 4; ++j)
                acc[i][j] = __builtin_amdgcn_mfma_f32_32x32x16_bf16(fah[i], fbh[j], acc[i][j], 0, 0, 0);
#pragma unroll
        for (int i = 0; i < 2; ++i)
#pragma unroll
            for (int j = 0; j < 4; ++j)
                acc[i][j] = __builtin_amdgcn_mfma_f32_32x32x16_bf16(fal[i], fbh[j], acc[i][j], 0, 0, 0);
#pragma unroll
        for (int i = 0; i < 2; ++i)
#pragma unroll
            for (int j = 0; j < 4; ++j)
                acc[i][j] = __builtin_amdgcn_mfma_f32_32x32x16_bf16(fah[i], fbl[j], acc[i][j], 0, 0, 0);
        __builtin_amdgcn_s_setprio(0);
    }
#undef STAGE

    // epilogue: per n-row (min1, idx, min2) over this wave's 128 k, then merge wk halves
    float esql[4];
#pragma unroll
    for (int j = 0; j < 4; ++j) esql[j] = esq[k0 + wk * 128 + j * 32 + lr];
#pragma unroll
    for (int i = 0; i < 2; ++i) {
#pragma unroll
        for (int r = 0; r < 16; ++r) {
            const int nl = (wn * 2 + i) * 32 + (r & 3) + 8 * (r >> 2) + 4 * lh;
            const float xs = xsq[n0 + nl];
            float m1 = 3.4e38f, m2 = 3.4e38f;
            int i1 = 0;
#pragma unroll
            for (int j = 0; j < 4; ++j) {
                float sv = (xs + esql[j]) - 2.0f * acc[i][j][r];
                int kg = k0 + wk * 128 + j * 32 + lr;
                if (sv < m1) { m2 = m1; m1 = sv; i1 = kg; }
                else m2 = fminf(m2, sv);
            }
#pragma unroll
            for (int off = 16; off >= 1; off >>= 1) {
                float om1 = __shfl_xor(m1, off, 64);
                float om2 = __shfl_xor(m2, off, 64);
                int   oi  = __shfl_xor(i1, off, 64);
                if (om1 < m1)      { m2 = fminf(m1, om2); m1 = om1; i1 = oi; }
                else if (om1 > m1) { m2 = fminf(m2, om1); }
                else               { m2 = m1; i1 = min(i1, oi); }
            }
            if (lr == 0) { lm1[wk][nl] = m1; lm2[wk][nl] = m2; li1[wk][nl] = i1; }
        }
    }
    __syncthreads();
    if (tid < 128) {
        float m1 = lm1[0][tid], m2 = lm2[0][tid];
        int i1 = li1[0][tid];
        float q1 = lm1[1][tid], q2 = lm2[1][tid];
        int qi = li1[1][tid];
        if (q1 < m1)      { m2 = fminf(m1, q2); m1 = q1; i1 = qi; }
        else if (q1 > m1) { m2 = fminf(m2, q1); }
        else              { m2 = m1; }   // wk ascending k: keep lower idx
        size_t p = (size_t)kb * N_VEC + n0 + tid;
        pm1[p] = m1; pm2[p] = m2; pix[p] = (unsigned short)i1;
    }
}

__global__ __launch_bounds__(256) void merge_kernel(
    const float* __restrict__ pm1, const float* __restrict__ pm2,
    const unsigned short* __restrict__ pix,
    int* __restrict__ screen_idx, unsigned* __restrict__ flag_list,
    unsigned* __restrict__ flag_count) {
    int n = blockIdx.x * 256 + threadIdx.x;
    float m1 = 3.4e38f, m2 = 3.4e38f;
    int i1 = 0;
    for (int kb = 0; kb < 4; ++kb) {
        size_t p = (size_t)kb * N_VEC + n;
        float a1 = pm1[p], a2 = pm2[p];
        int ai = (int)pix[p];
        if (a1 < m1)      { m2 = fminf(m1, a2); m1 = a1; i1 = ai; }
        else if (a1 > m1) { m2 = fminf(m2, a1); }
        else              { m2 = m1; i1 = min(i1, ai); }
    }
    if (m2 - m1 <= T_GAP) {
        screen_idx[n] = -1;
        unsigned pos = atomicAdd(flag_count, 1u);
        flag_list[pos] = (unsigned)n;
    } else {
        screen_idx[n] = i1;
    }
}

// ---------- exact-chain refine of flagged rows (8 rows/group) ----------

__global__ __launch_bounds__(256) void refine_kernel(
    const float* __restrict__ z, const float* __restrict__ embT,
    const float* __restrict__ esq, const float* __restrict__ xsq,
    const unsigned* __restrict__ flag_list, const unsigned* __restrict__ flag_count,
    float* __restrict__ out_idx, unsigned* __restrict__ counts) {
#pragma clang fp contract(off)
    __shared__ float zrow[8][256];
    __shared__ int nrow[8];
    __shared__ unsigned long long red[8][4];
    const int tid = threadIdx.x;
    const unsigned cnt = *flag_count;
    const unsigned groups = (cnt + 7) >> 3;
    const int kbase = tid * 4;
    for (unsigned g = blockIdx.x; g < groups; g += gridDim.x) {
        __syncthreads();
        if (tid < 8) nrow[tid] = (g * 8 + tid < cnt) ? (int)flag_list[g * 8 + tid] : -1;
        __syncthreads();
        for (int r = 0; r < 8; ++r) {
            int n = nrow[r];
            if (n >= 0) {
                int b = n >> 14, s = n & 16383;
                zrow[r][tid] = z[((size_t)b << 22) + ((size_t)tid << 14) + s];
            }
        }
        __syncthreads();
        float acc[8][4];
#pragma unroll
        for (int r = 0; r < 8; ++r)
#pragma unroll
            for (int j = 0; j < 4; ++j) acc[r][j] = 0.0f;
        for (int c4 = 0; c4 < 64; ++c4) {
            float4 ek[4];
#pragma unroll
            for (int x = 0; x < 4; ++x)
                ek[x] = *reinterpret_cast<const float4*>(embT + (size_t)(c4 * 4 + x) * K_CODES + kbase);
#pragma unroll
            for (int r = 0; r < 8; ++r) {
                float4 zv = *reinterpret_cast<const float4*>(&zrow[r][c4 * 4]);
                float a;
                a = acc[r][0];
                a = fmaf(zv.x, ek[0].x, a); a = fmaf(zv.y, ek[1].x, a);
                a = fmaf(zv.z, ek[2].x, a); a = fmaf(zv.w, ek[3].x, a);
                acc[r][0] = a;
                a = acc[r][1];
                a = fmaf(zv.x, ek[0].y, a); a = fmaf(zv.y, ek[1].y, a);
                a = fmaf(zv.z, ek[2].y, a); a = fmaf(zv.w, ek[3].y, a);
                acc[r][1] = a;
                a = acc[r][2];
                a = fmaf(zv.x, ek[0].z, a); a = fmaf(zv.y, ek[1].z, a);
                a = fmaf(zv.z, ek[2].z, a); a = fmaf(zv.w, ek[3].z, a);
                acc[r][2] = a;
                a = acc[r][3];
                a = fmaf(zv.x, ek[0].w, a); a = fmaf(zv.y, ek[1].w, a);
                a = fmaf(zv.z, ek[2].w, a); a = fmaf(zv.w, ek[3].w, a);
                acc[r][3] = a;
            }
        }
        float esql[4];
#pragma unroll
        for (int j = 0; j < 4; ++j) esql[j] = esq[kbase + j];
#pragma unroll
        for (int r = 0; r < 8; ++r) {
            int n = nrow[r];
            float xs = (n >= 0) ? xsq[n] : 0.0f;
            float m = 3.4e38f;
            int mi = 0;
#pragma unroll
            for (int j = 0; j < 4; ++j) {
                float t1 = xs + esql[j];
                float d = t1 - 2.0f * acc[r][j];
                if (d < m) { m = d; mi = kbase + j; }
            }
            unsigned long long p = ((unsigned long long)__float_as_uint(m) << 32) | (unsigned)mi;
            for (int off = 32; off >= 1; off >>= 1) {
                unsigned long long o = __shfl_xor(p, off, 64);
                p = (o < p) ? o : p;
            }
            if ((tid & 63) == 0) red[r][tid >> 6] = p;
        }
        __syncthreads();
        if (tid < 8 && nrow[tid] >= 0) {
            unsigned long long p = red[tid][0];
#pragma unroll
            for (int ww = 1; ww < 4; ++ww) { unsigned long long o = red[tid][ww]; p = (o < p) ? o : p; }
            int idx = (int)(p & 0xFFFFFFFFull);
            out_idx[nrow[tid]] = (float)idx;
            atomicAdd(&counts[idx], 1u);
        }
    }
}

__global__ __launch_bounds__(256) void emit_kernel(const int* __restrict__ screen_idx,
                                                   float* __restrict__ out_idx,
                                                   unsigned* __restrict__ counts) {
    int n = blockIdx.x * 256 + threadIdx.x;
    int iv = screen_idx[n];
    if (iv >= 0) {
        out_idx[n] = (float)iv;
        atomicAdd(&counts[iv], 1u);
    }
}

// ---------- gather + losses (validated) ----------

__global__ __launch_bounds__(256) void gather_kernel(
    const float* __restrict__ z, const float* __restrict__ embT,
    const float* __restrict__ out_idx, float* __restrict__ out,
    double* __restrict__ loss_acc) {
    const int tid = threadIdx.x;
    const int ct = blockIdx.x & 3;
    const int st = (blockIdx.x >> 2) & 15;
    const int b  = blockIdx.x >> 6;
    const int s0 = st * 1024;
    const int c0 = ct * 64;

    int idx[4];
#pragma unroll
    for (int q = 0; q < 4; ++q)
        idx[q] = (int)out_idx[(b << 14) + s0 + 4 * tid + q];

    const float* zb = z + ((size_t)b << 22) + s0 + 4 * tid;
    float* ob = out + ((size_t)b << 22) + s0 + 4 * tid;

    double local = 0.0;
    for (int c = 0; c < 64; ++c) {
        const int cg = c0 + c;
        const float* er = embT + (size_t)cg * K_CODES;
        float4 zv = *reinterpret_cast<const float4*>(zb + ((size_t)cg << 14));
        float4 ov;
        float d0 = er[idx[0]] - zv.x;
        float d1 = er[idx[1]] - zv.y;
        float d2 = er[idx[2]] - zv.z;
        float d3 = er[idx[3]] - zv.w;
        ov.x = zv.x + d0; ov.y = zv.y + d1; ov.z = zv.z + d2; ov.w = zv.w + d3;
        *reinterpret_cast<float4*>(ob + ((size_t)cg << 14)) = ov;
        local += (double)d0 * d0 + (double)d1 * d1 + (double)d2 * d2 + (double)d3 * d3;
    }
    for (int off = 32; off >= 1; off >>= 1) local += __shfl_down(local, off, 64);
    __shared__ double redd[4];
    if ((tid & 63) == 0) redd[tid >> 6] = local;
    __syncthreads();
    if (tid == 0) atomicAdd(loss_acc, redd[0] + redd[1] + redd[2] + redd[3]);
}

__global__ void finalize_kernel(const unsigned* __restrict__ counts,
                                const double* __restrict__ loss_acc,
                                float* __restrict__ out) {
    int tid = threadIdx.x;
    double s = 0.0;
    for (int k = tid; k < K_CODES; k += 256) {
        float avg = (float)counts[k] / 65536.0f;
        float t = avg * logf(avg + 1e-10f);
        s += (double)t;
    }
    for (int off = 32; off >= 1; off >>= 1) s += __shfl_down(s, off, 64);
    __shared__ double red[4];
    if ((tid & 63) == 0) red[tid >> 6] = s;
    __syncthreads();
    if (tid == 0) {
        double tot = red[0] + red[1] + red[2] + red[3];
        out[OUT_PP_OFF]   = expf((float)(-tot));
        out[OUT_LOSS_OFF] = 1.25f * (float)(loss_acc[0] / 16777216.0);
    }
}

extern "C" void kernel_launch(void* const* d_in, const int* in_sizes, int n_in,
                              void* d_out, int out_size, void* d_ws, size_t ws_size,
                              hipStream_t stream) {
    const float* z   = (const float*)d_in[0];
    const float* emb = (const float*)d_in[1];
    float* out = (float*)d_out;
    char* ws = (char*)d_ws;

    unsigned short* ehF = (unsigned short*)(ws + WS_EH);
    unsigned short* elF = (unsigned short*)(ws + WS_EL);
    float*    esq       = (float*)(ws + WS_ESQ);
    float*    xsq       = (float*)(ws + WS_XSQ);
    unsigned* counts    = (unsigned*)(ws + WS_CNT);
    double*   loss_acc  = (double*)(ws + WS_LOSS);
    unsigned* flag_cnt  = (unsigned*)(ws + WS_FLC);
    int*      sidx      = (int*)(ws + WS_SIDX);
    unsigned* flist     = (unsigned*)(ws + WS_FLIST);
    float*    pm1       = (float*)(ws + WS_PM1);
    float*    pm2       = (float*)(ws + WS_PM2);
    unsigned short* pix = (unsigned short*)(ws + WS_PIX);
    float*    embT      = (float*)(ws + WS_EMBT);

    unsigned short* zhF = (unsigned short*)out;                // [0, 33.5 MB)
    unsigned short* zlF = (unsigned short*)(out + 8388608);    // [33.5, 67 MB)
    float* out_idx = out + OUT_IDX_OFF;

    hipMemsetAsync(ws + WS_CNT, 0, 4108, stream);   // counts + loss + flag_count

    convert_z_kernel<<<1024, 256, 0, stream>>>(z, zhF, zlF);
    convert_e_kernel<<<128, 256, 0, stream>>>(emb, ehF, elF);
    esq_kernel<<<K_CODES / 64, 256, 0, stream>>>(emb, esq);
    xsq_kernel<<<N_VEC / 256, 256, 0, stream>>>(z, xsq);
    screen_kernel<<<2048, 256, 0, stream>>>(zhF, zlF, ehF, elF, esq, xsq, pm1, pm2, pix);
    merge_kernel<<<256, 256, 0, stream>>>(pm1, pm2, pix, sidx, flist, flag_cnt);
    transpose_kernel<<<dim3(16, 4), 256, 0, stream>>>(emb, embT);   // embT overlays pm1
    refine_kernel<<<1024, 256, 0, stream>>>(z, embT, esq, xsq, flist, flag_cnt, out_idx, counts);
    emit_kernel<<<256, 256, 0, stream>>>(sidx, out_idx, counts);
    gather_kernel<<<256, 256, 0, stream>>>(z, embT, out_idx, out, loss_acc);
    finalize_kernel<<<1, 256, 0, stream>>>(counts, loss_acc, out);
}

// Round 12
// 276.573 us; speedup vs baseline: 1.3320x; 1.3320x over previous
//
#include <hip/hip_runtime.h>

// VQ-VAE vector quantizer, MI355X — MFMA screen (E-in-registers as A-operand,
// z-streamed as B-operand, lane-local k fold) + exact-chain refine.
// z: (4,256,16,32,32) f32 ; emb: (1024,256) f32
// out (f32): z_q_st[16777216] | vq_loss | perplexity | indices[65536]
//
// Exactness contract (validated rounds 2-10, absmax 0):
//   x_sq[n], e_sq[k]: numpy pairwise sum of fl32(v*v) (two 128-blocks, 8 accs)
//   xe[n][k]: single sequential f32 FMA chain over c=0..255
//   d = fl32( fl32(x_sq+e_sq) - 2*xe ), argmin first-min tie-break.
// Screen = bf16-split MFMA (eh*zh + eh*zl + el*zh per q, ascending q);
// rows with merged (min2-min1) <= T_GAP=4e-4 (>> ~7e-5 screen-error bound)
// are recomputed by the bit-exact scalar chain (refine). Screen imprecision
// only increases flag rate, never wrongness.
//
// Round-12: r11 had two races: (a) depth-2 prefetch into a DOUBLE buffer
// (STAGE(s+2) overwrote the buffer being read); (b) raw s_barrier after the
// fold's LDS writes without lgkmcnt(0). Fixed: depth-1 prefetch (STAGE(s+1)
// after top barrier; loads covered by the 96-MFMA phase), explicit
// lgkmcnt(0) before the post-fold barrier. Also swapped MFMA operands:
// D[row=k][col=n] makes k lane-local -> fold = 15 register compares +
// one shfl_xor(32), killing r11's ~480 bpermutes/wave/window.

#define C_DIM 256
#define K_CODES 1024
#define N_VEC 65536
#define T_GAP 4e-4f

#define OUT_ZQ_SIZE 16777216
#define OUT_LOSS_OFF 16777216
#define OUT_PP_OFF   16777217
#define OUT_IDX_OFF  16777218

// ws layout (bytes)
#define WS_EH    0          // bf16 frag-major [32 kt][16 q][64 l][8]   512 KB
#define WS_EL    524288     // same                                     512 KB
#define WS_ESQ   1048576    // f32 [1024]
#define WS_XSQ   1052672    // f32 [65536]
#define WS_CNT   1314816    // u32 counts[1024]
#define WS_LOSS  1318912    // f64 loss
#define WS_FLC   1318920    // u32 flag count
#define WS_SIDX  1318928    // i32 screen_idx[65536]
#define WS_FLIST 1581072    // u32 flag_list[65536]
#define WS_PM1   1843264    // f32 [4][65536]
#define WS_EMBT  1843264    // f32 [256][1024] (overlays PM1 after merge)
#define WS_PM2   2891840    // f32 [4][65536]
#define WS_PIX   3940416    // u16 [4][65536]  (ends 4464704)

typedef __attribute__((ext_vector_type(8))) short short8;
typedef __attribute__((ext_vector_type(8))) unsigned short ushort8;
typedef __attribute__((ext_vector_type(16))) float f32x16;

__device__ __forceinline__ unsigned short bf16_rne(float v) {
    unsigned u = __float_as_uint(v);
    unsigned r = (u + 0x7FFFu + ((u >> 16) & 1u)) >> 16;
    return (unsigned short)r;
}

// fragment-major address (in shorts) of element (row, c) within a panel:
//   tile = row>>5, q = c>>4, lane = (row&31) + 32*((c>>3)&1), j = c&7
//   off  = tile*8192 + q*512 + lane*8 + j

// ---------- conversions ----------

__global__ __launch_bounds__(256) void convert_z_kernel(const float* __restrict__ z,
                                                        unsigned short* __restrict__ zhF,
                                                        unsigned short* __restrict__ zlF) {
    const int tid = threadIdx.x;
    const int ln = tid & 63;
    const int og = tid >> 6;
    const int n0 = blockIdx.x * 64;
    const int b = n0 >> 14, s0 = n0 & 16383;
    const int n = n0 + ln;
    const size_t zbase = ((size_t)b << 22) + s0 + ln;
    const size_t tbase = (size_t)(n >> 5) * 8192;
    const int lr = n & 31;
#pragma unroll
    for (int t = 0; t < 8; ++t) {
        int o = og + t * 4;        // c-octet 0..31
        int c0 = o * 8;
        ushort8 hb, lb;
#pragma unroll
        for (int j = 0; j < 8; ++j) {
            float v = z[zbase + ((size_t)(c0 + j) << 14)];
            unsigned short h = bf16_rne(v);
            hb[j] = h;
            lb[j] = bf16_rne(v - __uint_as_float((unsigned)h << 16));
        }
        size_t off = tbase + (size_t)(o >> 1) * 512 + (size_t)(lr + 32 * (o & 1)) * 8;
        *reinterpret_cast<ushort8*>(zhF + off) = hb;
        *reinterpret_cast<ushort8*>(zlF + off) = lb;
    }
}

__global__ __launch_bounds__(256) void convert_e_kernel(const float* __restrict__ emb,
                                                        unsigned short* __restrict__ ehF,
                                                        unsigned short* __restrict__ elF) {
    int t = blockIdx.x * 256 + threadIdx.x;   // 32768 threads
    int k = t >> 5, o = t & 31;
    int c0 = o * 8;
    ushort8 hb, lb;
#pragma unroll
    for (int j = 0; j < 8; ++j) {
        float v = emb[k * C_DIM + c0 + j];
        unsigned short h = bf16_rne(v);
        hb[j] = h;
        lb[j] = bf16_rne(v - __uint_as_float((unsigned)h << 16));
    }
    size_t off = (size_t)(k >> 5) * 8192 + (size_t)(o >> 1) * 512 + (size_t)((k & 31) + 32 * (o & 1)) * 8;
    *reinterpret_cast<ushort8*>(ehF + off) = hb;
    *reinterpret_cast<ushort8*>(elF + off) = lb;
}

// ---------- exact norms (validated) ----------

__device__ __forceinline__ float pairwise_sq_128(const float* p) {
#pragma clang fp contract(off)
    float r[8];
#pragma unroll
    for (int j = 0; j < 8; ++j) { float v = p[j]; r[j] = v * v; }
#pragma unroll
    for (int i = 8; i < 128; i += 8)
#pragma unroll
        for (int j = 0; j < 8; ++j) { float v = p[i + j]; float t = v * v; r[j] = r[j] + t; }
    return ((r[0] + r[1]) + (r[2] + r[3])) + ((r[4] + r[5]) + (r[6] + r[7]));
}

__global__ __launch_bounds__(256) void esq_kernel(const float* __restrict__ emb,
                                                  float* __restrict__ esq) {
#pragma clang fp contract(off)
    __shared__ float tile[64 * 260];
    const int tid = threadIdx.x;
    const int k0 = blockIdx.x * 64;
#pragma unroll
    for (int r = 0; r < 64; ++r) {
        int idx = r * 256 + tid;
        tile[(idx >> 8) * 260 + (idx & 255)] = emb[k0 * C_DIM + idx];
    }
    __syncthreads();
    if (tid < 64) {
        const float* row = &tile[tid * 260];
        esq[k0 + tid] = pairwise_sq_128(row) + pairwise_sq_128(row + 128);
    }
}

__global__ __launch_bounds__(256) void xsq_kernel(const float* __restrict__ z,
                                                  float* __restrict__ xsq) {
#pragma clang fp contract(off)
    const int n = blockIdx.x * 256 + threadIdx.x;
    const int b = n >> 14, s = n & 16383;
    const float* base = z + ((size_t)b << 22) + s;
    float r[8], res;
#pragma unroll
    for (int j = 0; j < 8; ++j) { float v = base[(size_t)j << 14]; r[j] = v * v; }
#pragma unroll
    for (int i = 8; i < 128; i += 8)
#pragma unroll
        for (int j = 0; j < 8; ++j) { float v = base[(size_t)(i + j) << 14]; float t = v * v; r[j] = r[j] + t; }
    res = ((r[0] + r[1]) + (r[2] + r[3])) + ((r[4] + r[5]) + (r[6] + r[7]));
#pragma unroll
    for (int j = 0; j < 8; ++j) { float v = base[(size_t)(128 + j) << 14]; r[j] = v * v; }
#pragma unroll
    for (int i = 136; i < 256; i += 8)
#pragma unroll
        for (int j = 0; j < 8; ++j) { float v = base[(size_t)(i + j) << 14]; float t = v * v; r[j] = r[j] + t; }
    res = res + (((r[0] + r[1]) + (r[2] + r[3])) + ((r[4] + r[5]) + (r[6] + r[7])));
    xsq[n] = res;
}

__global__ __launch_bounds__(256) void transpose_kernel(const float* __restrict__ emb,
                                                        float* __restrict__ embT) {
    __shared__ float t[64][65];
    const int k0 = blockIdx.x * 64;
    const int c0 = blockIdx.y * 64;
    const int tx = threadIdx.x & 63, ty = threadIdx.x >> 6;
    for (int r = ty; r < 64; r += 4)
        t[r][tx] = emb[(k0 + r) * C_DIM + c0 + tx];
    __syncthreads();
    for (int r = ty; r < 64; r += 4)
        embT[(c0 + r) * K_CODES + k0 + tx] = t[tx][r];
}

// ---------- MFMA screen: E-in-registers (A-operand), z-streamed (B-operand) ----------
// block: 512 threads = 8 waves; block covers 512n x 256k; grid 512 = 128 nb x 4 kb.
// D[row=k][col=n]: k is lane-local (16 regs) -> fold is register-min + 1 shfl.

__global__ __launch_bounds__(512, 1) void screen_kernel(
    const unsigned short* __restrict__ zhF, const unsigned short* __restrict__ zlF,
    const unsigned short* __restrict__ ehF, const unsigned short* __restrict__ elF,
    const float* __restrict__ esq, const float* __restrict__ xsq,
    float* __restrict__ pm1, float* __restrict__ pm2,
    unsigned short* __restrict__ pix) {
    __shared__ __align__(16) unsigned short abuf[2][64 * 512];   // 128 KB, double buffer
    __shared__ float xbuf[512];
    __shared__ float sm1[8][64], sm2[8][64];
    __shared__ int   si[8][64];

    const int tid = threadIdx.x;
    const int w = tid >> 6, l = tid & 63, lr = l & 31, lh = l >> 5;
    const int bid = blockIdx.x;
    const int v = (bid & 7) * 64 + (bid >> 3);   // XCD-chunked bijective swizzle (512 = 8*64)
    const int nb = v >> 2, kb = v & 3;
    const int n0 = nb * 512;
    const int kw = kb * 256 + w * 32;            // this wave's 32-k strip
    const int loff = l * 8;

    // ---- resident E (A-operand): one frag-major 32-k tile per wave ----
    short8 Eh[16], El[16];
    {
        const unsigned short* bh = ehF + (size_t)(kb * 8 + w) * 8192 + loff;
        const unsigned short* bl = elF + (size_t)(kb * 8 + w) * 8192 + loff;
#pragma unroll
        for (int q = 0; q < 16; ++q) {
            Eh[q] = *reinterpret_cast<const short8*>(bh + q * 512);
            El[q] = *reinterpret_cast<const short8*>(bl + q * 512);
        }
    }
    // per-lane e_sq for the 16 k-rows this lane sees (k = kw + crow(r,lh))
    float esql[16];
#pragma unroll
    for (int r = 0; r < 16; ++r)
        esql[r] = esq[kw + (r & 3) + 8 * (r >> 2) + 4 * lh];

    // xsq for the block's 512 n -> LDS (4B DMA per lane)
    __builtin_amdgcn_global_load_lds(
        (const __attribute__((address_space(1))) void*)(xsq + n0 + w * 64 + l),
        (__attribute__((address_space(3))) void*)&xbuf[w * 64], 4, 0, 0);

    asm volatile("s_waitcnt vmcnt(0)" ::: "memory");   // drain E + esql + xbuf
    __builtin_amdgcn_s_barrier();

    // ---- A staging: window s = 64n; chunks: [zh t0 q0-15 | zh t1 | zl t0 | zl t1] ----
#define STAGE(S) do {                                                                   \
    const int _b = (S) & 1;                                                             \
    _Pragma("unroll")                                                                   \
    for (int ci = 0; ci < 8; ++ci) {                                                    \
        int c = 8 * w + ci;                                                             \
        const unsigned short* src = ((c & 32) ? zlF : zhF)                              \
            + (size_t)((n0 >> 5) + (S) * 2 + ((c >> 4) & 1)) * 8192                     \
            + (size_t)(c & 15) * 512 + loff;                                            \
        __builtin_amdgcn_global_load_lds(                                               \
            (const __attribute__((address_space(1))) void*)src,                         \
            (__attribute__((address_space(3))) void*)&abuf[_b][c * 512], 16, 0, 0);     \
    }                                                                                   \
} while (0)

    STAGE(0);

    float rm1 = 3.4e38f, rm2 = 3.4e38f;   // this wave's merged result (window s == w)
    int   ri1 = 0;

    for (int s = 0; s < 8; ++s) {
        const int cur = s & 1;
        // depth-1: my 8 STAGE(s) loads are the only outstanding DMAs
        asm volatile("s_waitcnt vmcnt(0)" ::: "memory");
        __builtin_amdgcn_s_barrier();
        __builtin_amdgcn_sched_barrier(0);
        if (s < 7) STAGE(s + 1);   // into buffer cur^1: everyone finished reading it last step

        f32x16 acc0, acc1;
#pragma unroll
        for (int r = 0; r < 16; ++r) { acc0[r] = 0.0f; acc1[r] = 0.0f; }

        __builtin_amdgcn_s_setprio(1);
#pragma unroll
        for (int q = 0; q < 16; ++q) {
            short8 azh0 = *reinterpret_cast<const short8*>(&abuf[cur][(q)      * 512 + loff]);
            short8 azh1 = *reinterpret_cast<const short8*>(&abuf[cur][(16 + q) * 512 + loff]);
            short8 azl0 = *reinterpret_cast<const short8*>(&abuf[cur][(32 + q) * 512 + loff]);
            short8 azl1 = *reinterpret_cast<const short8*>(&abuf[cur][(48 + q) * 512 + loff]);
            acc0 = __builtin_amdgcn_mfma_f32_32x32x16_bf16(Eh[q], azh0, acc0, 0, 0, 0);
            acc1 = __builtin_amdgcn_mfma_f32_32x32x16_bf16(Eh[q], azh1, acc1, 0, 0, 0);
            acc0 = __builtin_amdgcn_mfma_f32_32x32x16_bf16(Eh[q], azl0, acc0, 0, 0, 0);
            acc1 = __builtin_amdgcn_mfma_f32_32x32x16_bf16(Eh[q], azl1, acc1, 0, 0, 0);
            acc0 = __builtin_amdgcn_mfma_f32_32x32x16_bf16(El[q], azh0, acc0, 0, 0, 0);
            acc1 = __builtin_amdgcn_mfma_f32_32x32x16_bf16(El[q], azh1, acc1, 0, 0, 0);
        }
        __builtin_amdgcn_s_setprio(0);

        // fold: lane's col n = lr (per tile); 16 k-rows live in acc registers
#pragma unroll
        for (int i = 0; i < 2; ++i) {
            const f32x16 a = i ? acc1 : acc0;
            const float xs = xbuf[s * 64 + i * 32 + lr];
            float m1 = 3.4e38f, m2 = 3.4e38f;
            int i1 = 0;
#pragma unroll
            for (int r = 0; r < 16; ++r) {            // kg ascending in r
                float sv = (xs + esql[r]) - 2.0f * a[r];
                int kg = kw + (r & 3) + 8 * (r >> 2) + 4 * lh;
                if (sv < m1) { m2 = m1; m1 = sv; i1 = kg; }
                else m2 = fminf(m2, sv);
            }
            // merge lh halves (disjoint k sets for same n)
            float om1 = __shfl_xor(m1, 32, 64);
            float om2 = __shfl_xor(m2, 32, 64);
            int   oi  = __shfl_xor(i1, 32, 64);
            if (om1 < m1)      { m2 = fminf(m1, om2); m1 = om1; i1 = oi; }
            else if (om1 > m1) { m2 = fminf(m2, om1); }
            else               { m2 = m1; i1 = min(i1, oi); }
            if (lh == 0) { sm1[w][i * 32 + lr] = m1; sm2[w][i * 32 + lr] = m2; si[w][i * 32 + lr] = i1; }
        }
        asm volatile("s_waitcnt lgkmcnt(0)" ::: "memory");   // publish sm before raw barrier
        __builtin_amdgcn_s_barrier();
        __builtin_amdgcn_sched_barrier(0);

        if (w == s) {   // wave s merges window s across the 8 k-strips (w asc = k asc)
            float m1 = sm1[0][l], m2 = sm2[0][l];
            int i1 = si[0][l];
#pragma unroll
            for (int ww = 1; ww < 8; ++ww) {
                float q1 = sm1[ww][l], q2 = sm2[ww][l];
                int qi = si[ww][l];
                if (q1 < m1)      { m2 = fminf(m1, q2); m1 = q1; i1 = qi; }
                else if (q1 > m1) { m2 = fminf(m2, q1); }
                else              { m2 = m1; }
            }
            rm1 = m1; rm2 = m2; ri1 = i1;
        }
    }
#undef STAGE

    // wave w owns window s==w: n = n0 + w*64 + l
    {
        size_t p = (size_t)kb * N_VEC + n0 + w * 64 + l;
        pm1[p] = rm1; pm2[p] = rm2; pix[p] = (unsigned short)ri1;
    }
}

__global__ __launch_bounds__(256) void merge_kernel(
    const float* __restrict__ pm1, const float* __restrict__ pm2,
    const unsigned short* __restrict__ pix,
    int* __restrict__ screen_idx, unsigned* __restrict__ flag_list,
    unsigned* __restrict__ flag_count) {
    int n = blockIdx.x * 256 + threadIdx.x;
    float m1 = 3.4e38f, m2 = 3.4e38f;
    int i1 = 0;
    for (int kb = 0; kb < 4; ++kb) {
        size_t p = (size_t)kb * N_VEC + n;
        float a1 = pm1[p], a2 = pm2[p];
        int ai = (int)pix[p];
        if (a1 < m1)      { m2 = fminf(m1, a2); m1 = a1; i1 = ai; }
        else if (a1 > m1) { m2 = fminf(m2, a1); }
        else              { m2 = m1; i1 = min(i1, ai); }
    }
    if (m2 - m1 <= T_GAP) {
        screen_idx[n] = -1;
        unsigned pos = atomicAdd(flag_count, 1u);
        flag_list[pos] = (unsigned)n;
    } else {
        screen_idx[n] = i1;
    }
}

// ---------- exact-chain refine of flagged rows (8 rows/group) ----------

__global__ __launch_bounds__(256) void refine_kernel(
    const float* __restrict__ z, const float* __restrict__ embT,
    const float* __restrict__ esq, const float* __restrict__ xsq,
    const unsigned* __restrict__ flag_list, const unsigned* __restrict__ flag_count,
    float* __restrict__ out_idx, unsigned* __restrict__ counts) {
#pragma clang fp contract(off)
    __shared__ float zrow[8][256];
    __shared__ int nrow[8];
    __shared__ unsigned long long red[8][4];
    const int tid = threadIdx.x;
    const unsigned cnt = *flag_count;
    const unsigned groups = (cnt + 7) >> 3;
    const int kbase = tid * 4;
    for (unsigned g = blockIdx.x; g < groups; g += gridDim.x) {
        __syncthreads();
        if (tid < 8) nrow[tid] = (g * 8 + tid < cnt) ? (int)flag_list[g * 8 + tid] : -1;
        __syncthreads();
        for (int r = 0; r < 8; ++r) {
            int n = nrow[r];
            if (n >= 0) {
                int b = n >> 14, s = n & 16383;
                zrow[r][tid] = z[((size_t)b << 22) + ((size_t)tid << 14) + s];
            }
        }
        __syncthreads();
        float acc[8][4];
#pragma unroll
        for (int r = 0; r < 8; ++r)
#pragma unroll
            for (int j = 0; j < 4; ++j) acc[r][j] = 0.0f;
        for (int c4 = 0; c4 < 64; ++c4) {
            float4 ek[4];
#pragma unroll
            for (int x = 0; x < 4; ++x)
                ek[x] = *reinterpret_cast<const float4*>(embT + (size_t)(c4 * 4 + x) * K_CODES + kbase);
#pragma unroll
            for (int r = 0; r < 8; ++r) {
                float4 zv = *reinterpret_cast<const float4*>(&zrow[r][c4 * 4]);
                float a;
                a = acc[r][0];
                a = fmaf(zv.x, ek[0].x, a); a = fmaf(zv.y, ek[1].x, a);
                a = fmaf(zv.z, ek[2].x, a); a = fmaf(zv.w, ek[3].x, a);
                acc[r][0] = a;
                a = acc[r][1];
                a = fmaf(zv.x, ek[0].y, a); a = fmaf(zv.y, ek[1].y, a);
                a = fmaf(zv.z, ek[2].y, a); a = fmaf(zv.w, ek[3].y, a);
                acc[r][1] = a;
                a = acc[r][2];
                a = fmaf(zv.x, ek[0].z, a); a = fmaf(zv.y, ek[1].z, a);
                a = fmaf(zv.z, ek[2].z, a); a = fmaf(zv.w, ek[3].z, a);
                acc[r][2] = a;
                a = acc[r][3];
                a = fmaf(zv.x, ek[0].w, a); a = fmaf(zv.y, ek[1].w, a);
                a = fmaf(zv.z, ek[2].w, a); a = fmaf(zv.w, ek[3].w, a);
                acc[r][3] = a;
            }
        }
        float esql[4];
#pragma unroll
        for (int j = 0; j < 4; ++j) esql[j] = esq[kbase + j];
#pragma unroll
        for (int r = 0; r < 8; ++r) {
            int n = nrow[r];
            float xs = (n >= 0) ? xsq[n] : 0.0f;
            float m = 3.4e38f;
            int mi = 0;
#pragma unroll
            for (int j = 0; j < 4; ++j) {
                float t1 = xs + esql[j];
                float d = t1 - 2.0f * acc[r][j];
                if (d < m) { m = d; mi = kbase + j; }
            }
            unsigned long long p = ((unsigned long long)__float_as_uint(m) << 32) | (unsigned)mi;
            for (int off = 32; off >= 1; off >>= 1) {
                unsigned long long o = __shfl_xor(p, off, 64);
                p = (o < p) ? o : p;
            }
            if ((tid & 63) == 0) red[r][tid >> 6] = p;
        }
        __syncthreads();
        if (tid < 8 && nrow[tid] >= 0) {
            unsigned long long p = red[tid][0];
#pragma unroll
            for (int ww = 1; ww < 4; ++ww) { unsigned long long o = red[tid][ww]; p = (o < p) ? o : p; }
            int idx = (int)(p & 0xFFFFFFFFull);
            out_idx[nrow[tid]] = (float)idx;
            atomicAdd(&counts[idx], 1u);
        }
    }
}

__global__ __launch_bounds__(256) void emit_kernel(const int* __restrict__ screen_idx,
                                                   float* __restrict__ out_idx,
                                                   unsigned* __restrict__ counts) {
    int n = blockIdx.x * 256 + threadIdx.x;
    int iv = screen_idx[n];
    if (iv >= 0) {
        out_idx[n] = (float)iv;
        atomicAdd(&counts[iv], 1u);
    }
}

// ---------- gather + losses (validated) ----------

__global__ __launch_bounds__(256) void gather_kernel(
    const float* __restrict__ z, const float* __restrict__ embT,
    const float* __restrict__ out_idx, float* __restrict__ out,
    double* __restrict__ loss_acc) {
    const int tid = threadIdx.x;
    const int ct = blockIdx.x & 3;
    const int st = (blockIdx.x >> 2) & 15;
    const int b  = blockIdx.x >> 6;
    const int s0 = st * 1024;
    const int c0 = ct * 64;

    int idx[4];
#pragma unroll
    for (int q = 0; q < 4; ++q)
        idx[q] = (int)out_idx[(b << 14) + s0 + 4 * tid + q];

    const float* zb = z + ((size_t)b << 22) + s0 + 4 * tid;
    float* ob = out + ((size_t)b << 22) + s0 + 4 * tid;

    double local = 0.0;
    for (int c = 0; c < 64; ++c) {
        const int cg = c0 + c;
        const float* er = embT + (size_t)cg * K_CODES;
        float4 zv = *reinterpret_cast<const float4*>(zb + ((size_t)cg << 14));
        float4 ov;
        float d0 = er[idx[0]] - zv.x;
        float d1 = er[idx[1]] - zv.y;
        float d2 = er[idx[2]] - zv.z;
        float d3 = er[idx[3]] - zv.w;
        ov.x = zv.x + d0; ov.y = zv.y + d1; ov.z = zv.z + d2; ov.w = zv.w + d3;
        *reinterpret_cast<float4*>(ob + ((size_t)cg << 14)) = ov;
        local += (double)d0 * d0 + (double)d1 * d1 + (double)d2 * d2 + (double)d3 * d3;
    }
    for (int off = 32; off >= 1; off >>= 1) local += __shfl_down(local, off, 64);
    __shared__ double redd[4];
    if ((tid & 63) == 0) redd[tid >> 6] = local;
    __syncthreads();
    if (tid == 0) atomicAdd(loss_acc, redd[0] + redd[1] + redd[2] + redd[3]);
}

__global__ void finalize_kernel(const unsigned* __restrict__ counts,
                                const double* __restrict__ loss_acc,
                                float* __restrict__ out) {
    int tid = threadIdx.x;
    double s = 0.0;
    for (int k = tid; k < K_CODES; k += 256) {
        float avg = (float)counts[k] / 65536.0f;
        float t = avg * logf(avg + 1e-10f);
        s += (double)t;
    }
    for (int off = 32; off >= 1; off >>= 1) s += __shfl_down(s, off, 64);
    __shared__ double red[4];
    if ((tid & 63) == 0) red[tid >> 6] = s;
    __syncthreads();
    if (tid == 0) {
        double tot = red[0] + red[1] + red[2] + red[3];
        out[OUT_PP_OFF]   = expf((float)(-tot));
        out[OUT_LOSS_OFF] = 1.25f * (float)(loss_acc[0] / 16777216.0);
    }
}

extern "C" void kernel_launch(void* const* d_in, const int* in_sizes, int n_in,
                              void* d_out, int out_size, void* d_ws, size_t ws_size,
                              hipStream_t stream) {
    const float* z   = (const float*)d_in[0];
    const float* emb = (const float*)d_in[1];
    float* out = (float*)d_out;
    char* ws = (char*)d_ws;

    unsigned short* ehF = (unsigned short*)(ws + WS_EH);
    unsigned short* elF = (unsigned short*)(ws + WS_EL);
    float*    esq       = (float*)(ws + WS_ESQ);
    float*    xsq       = (float*)(ws + WS_XSQ);
    unsigned* counts    = (unsigned*)(ws + WS_CNT);
    double*   loss_acc  = (double*)(ws + WS_LOSS);
    unsigned* flag_cnt  = (unsigned*)(ws + WS_FLC);
    int*      sidx      = (int*)(ws + WS_SIDX);
    unsigned* flist     = (unsigned*)(ws + WS_FLIST);
    float*    pm1       = (float*)(ws + WS_PM1);
    float*    pm2       = (float*)(ws + WS_PM2);
    unsigned short* pix = (unsigned short*)(ws + WS_PIX);
    float*    embT      = (float*)(ws + WS_EMBT);

    unsigned short* zhF = (unsigned short*)out;                // [0, 33.5 MB)
    unsigned short* zlF = (unsigned short*)(out + 8388608);    // [33.5, 67 MB)
    float* out_idx = out + OUT_IDX_OFF;

    hipMemsetAsync(ws + WS_CNT, 0, 4108, stream);   // counts + loss + flag_count

    convert_z_kernel<<<1024, 256, 0, stream>>>(z, zhF, zlF);
    convert_e_kernel<<<128, 256, 0, stream>>>(emb, ehF, elF);
    esq_kernel<<<K_CODES / 64, 256, 0, stream>>>(emb, esq);
    xsq_kernel<<<N_VEC / 256, 256, 0, stream>>>(z, xsq);
    screen_kernel<<<512, 512, 0, stream>>>(zhF, zlF, ehF, elF, esq, xsq, pm1, pm2, pix);
    merge_kernel<<<256, 256, 0, stream>>>(pm1, pm2, pix, sidx, flist, flag_cnt);
    transpose_kernel<<<dim3(16, 4), 256, 0, stream>>>(emb, embT);   // embT overlays pm1
    refine_kernel<<<1024, 256, 0, stream>>>(z, embT, esq, xsq, flist, flag_cnt, out_idx, counts);
    emit_kernel<<<256, 256, 0, stream>>>(sidx, out_idx, counts);
    gather_kernel<<<256, 256, 0, stream>>>(z, embT, out_idx, out, loss_acc);
    finalize_kernel<<<1, 256, 0, stream>>>(counts, loss_acc, out);
}

// Round 13
// 244.970 us; speedup vs baseline: 1.5038x; 1.1290x over previous
//
#include <hip/hip_runtime.h>

// VQ-VAE vector quantizer, MI355X — MFMA screen (E-in-registers, z-streamed,
// single-barrier pipeline) + exact-chain refine. Fused aux kernels.
// z: (4,256,16,32,32) f32 ; emb: (1024,256) f32
// out (f32): z_q_st[16777216] | vq_loss | perplexity | indices[65536]
//
// Exactness contract (validated rounds 2-12, absmax 0):
//   x_sq[n], e_sq[k]: numpy pairwise sum of fl32(v*v) (two 128-blocks, 8 accs)
//   xe[n][k]: single sequential f32 FMA chain over c=0..255
//   d = fl32( fl32(x_sq+e_sq) - 2*xe ), argmin first-min tie-break.
// Screen = bf16-split MFMA (eh*zh + eh*zl + el*zh, same acc order as r12);
// rows with merged (min2-min1) <= T_GAP=4e-4 (>> ~7e-5 screen-error bound)
// are recomputed by the bit-exact scalar chain (refine).
//
// Round-13 (r12 screen validated at 135us): (1) xsq fused into convert_z
// (pairwise from the staged LDS tile, strided, bit-identical order) — saves a
// 67 MB z pass + launch; (2) esq fused into convert_e; (3) emit fused into
// merge (sidx dropped); (4) screen loop: 2 barriers/step -> 1 via parity-
// double-buffered sm + deferred merge (window s merged by wave s at step s+1).

#define C_DIM 256
#define K_CODES 1024
#define N_VEC 65536
#define T_GAP 4e-4f

#define OUT_ZQ_SIZE 16777216
#define OUT_LOSS_OFF 16777216
#define OUT_PP_OFF   16777217
#define OUT_IDX_OFF  16777218

// ws layout (bytes)
#define WS_EH    0          // bf16 frag-major [32 kt][16 q][64 l][8]   512 KB
#define WS_EL    524288     // same                                     512 KB
#define WS_ESQ   1048576    // f32 [1024]
#define WS_XSQ   1052672    // f32 [65536]
#define WS_CNT   1314816    // u32 counts[1024]
#define WS_LOSS  1318912    // f64 loss
#define WS_FLC   1318920    // u32 flag count
#define WS_FLIST 1581072    // u32 flag_list[65536]
#define WS_PM1   1843264    // f32 [4][65536]
#define WS_EMBT  1843264    // f32 [256][1024] (overlays PM1 after merge)
#define WS_PM2   2891840    // f32 [4][65536]
#define WS_PIX   3940416    // u16 [4][65536]  (ends 4464704)

typedef __attribute__((ext_vector_type(8))) short short8;
typedef __attribute__((ext_vector_type(8))) unsigned short ushort8;
typedef __attribute__((ext_vector_type(16))) float f32x16;

__device__ __forceinline__ unsigned short bf16_rne(float v) {
    unsigned u = __float_as_uint(v);
    unsigned r = (u + 0x7FFFu + ((u >> 16) & 1u)) >> 16;
    return (unsigned short)r;
}

// fragment-major address (in shorts) of element (row, c) within a panel:
//   tile = row>>5, q = c>>4, lane = (row&31) + 32*((c>>3)&1), j = c&7
//   off  = tile*8192 + q*512 + lane*8 + j

// ---------- conversions (xsq fused into convert_z; esq fused into convert_e) ----------

__global__ __launch_bounds__(256) void convert_z_kernel(const float* __restrict__ z,
                                                        unsigned short* __restrict__ zhF,
                                                        unsigned short* __restrict__ zlF,
                                                        float* __restrict__ xsq) {
#pragma clang fp contract(off)
    __shared__ float tile[128][65];
    const int tid = threadIdx.x;
    const int ln = tid & 63;
    const int og = tid >> 6;
    const int n0 = blockIdx.x * 64;
    const int b = n0 >> 14, s0 = n0 & 16383;
    const int n = n0 + ln;
    const size_t tbase = (size_t)(n >> 5) * 8192;
    const int lr = n & 31;
    float res = 0.0f;

    for (int p = 0; p < 2; ++p) {
        __syncthreads();
        for (int i = 0; i < 32; ++i) {
            int c = p * 128 + i * 4 + og;
            tile[i * 4 + og][ln] = z[((size_t)b << 22) + ((size_t)c << 14) + s0 + ln];
        }
        __syncthreads();
        // frag-major bf16 split writes (4 c-octets per thread in this half)
#pragma unroll
        for (int t = 0; t < 4; ++t) {
            int oh = og + t * 4;               // octet within half, 0..15
            int o  = p * 16 + oh;              // global c-octet 0..31
            ushort8 hb, lb;
#pragma unroll
            for (int j = 0; j < 8; ++j) {
                float v = tile[oh * 8 + j][ln];
                unsigned short h = bf16_rne(v);
                hb[j] = h;
                lb[j] = bf16_rne(v - __uint_as_float((unsigned)h << 16));
            }
            size_t off = tbase + (size_t)(o >> 1) * 512 + (size_t)(lr + 32 * (o & 1)) * 8;
            *reinterpret_cast<ushort8*>(zhF + off) = hb;
            *reinterpret_cast<ushort8*>(zlF + off) = lb;
        }
        // numpy pairwise 128-block for this c-half (strided LDS reads, exact order)
        if (tid < 64) {
            float r[8];
#pragma unroll
            for (int j = 0; j < 8; ++j) { float v = tile[j][tid]; r[j] = v * v; }
#pragma unroll
            for (int i = 8; i < 128; i += 8)
#pragma unroll
                for (int j = 0; j < 8; ++j) { float v = tile[i + j][tid]; float t2 = v * v; r[j] = r[j] + t2; }
            float blk = ((r[0] + r[1]) + (r[2] + r[3])) + ((r[4] + r[5]) + (r[6] + r[7]));
            res = (p == 0) ? blk : res + blk;
        }
    }
    if (tid < 64) xsq[n0 + tid] = res;
}

__device__ __forceinline__ float pairwise_sq_128(const float* p) {
#pragma clang fp contract(off)
    float r[8];
#pragma unroll
    for (int j = 0; j < 8; ++j) { float v = p[j]; r[j] = v * v; }
#pragma unroll
    for (int i = 8; i < 128; i += 8)
#pragma unroll
        for (int j = 0; j < 8; ++j) { float v = p[i + j]; float t = v * v; r[j] = r[j] + t; }
    return ((r[0] + r[1]) + (r[2] + r[3])) + ((r[4] + r[5]) + (r[6] + r[7]));
}

__global__ __launch_bounds__(256) void convert_e_kernel(const float* __restrict__ emb,
                                                        unsigned short* __restrict__ ehF,
                                                        unsigned short* __restrict__ elF,
                                                        float* __restrict__ esq) {
#pragma clang fp contract(off)
    int t = blockIdx.x * 256 + threadIdx.x;   // 32768 threads
    int k = t >> 5, o = t & 31;
    int c0 = o * 8;
    ushort8 hb, lb;
#pragma unroll
    for (int j = 0; j < 8; ++j) {
        float v = emb[k * C_DIM + c0 + j];
        unsigned short h = bf16_rne(v);
        hb[j] = h;
        lb[j] = bf16_rne(v - __uint_as_float((unsigned)h << 16));
    }
    size_t off = (size_t)(k >> 5) * 8192 + (size_t)(o >> 1) * 512 + (size_t)((k & 31) + 32 * (o & 1)) * 8;
    *reinterpret_cast<ushort8*>(ehF + off) = hb;
    *reinterpret_cast<ushort8*>(elF + off) = lb;
    // esq for this block's 8 k-rows (L1-hot), exact numpy pairwise
    if (threadIdx.x < 8) {
        int k8 = blockIdx.x * 8 + threadIdx.x;
        const float* row = emb + (size_t)k8 * C_DIM;
        esq[k8] = pairwise_sq_128(row) + pairwise_sq_128(row + 128);
    }
}

__global__ __launch_bounds__(256) void transpose_kernel(const float* __restrict__ emb,
                                                        float* __restrict__ embT) {
    __shared__ float t[64][65];
    const int k0 = blockIdx.x * 64;
    const int c0 = blockIdx.y * 64;
    const int tx = threadIdx.x & 63, ty = threadIdx.x >> 6;
    for (int r = ty; r < 64; r += 4)
        t[r][tx] = emb[(k0 + r) * C_DIM + c0 + tx];
    __syncthreads();
    for (int r = ty; r < 64; r += 4)
        embT[(c0 + r) * K_CODES + k0 + tx] = t[tx][r];
}

// ---------- MFMA screen: E-in-registers (A-operand), z-streamed (B-operand) ----------
// block: 512 threads = 8 waves; block covers 512n x 256k; grid 512 = 128 nb x 4 kb.
// Single barrier per step; window s merged (by wave s) at step s+1 from
// parity-double-buffered sm.

__global__ __launch_bounds__(512, 1) void screen_kernel(
    const unsigned short* __restrict__ zhF, const unsigned short* __restrict__ zlF,
    const unsigned short* __restrict__ ehF, const unsigned short* __restrict__ elF,
    const float* __restrict__ esq, const float* __restrict__ xsq,
    float* __restrict__ pm1, float* __restrict__ pm2,
    unsigned short* __restrict__ pix) {
    __shared__ __align__(16) unsigned short abuf[2][64 * 512];   // 128 KB, double buffer
    __shared__ float xbuf[512];
    __shared__ float smp1[2][8][64], smp2[2][8][64];
    __shared__ int   smi[2][8][64];

    const int tid = threadIdx.x;
    const int w = tid >> 6, l = tid & 63, lr = l & 31, lh = l >> 5;
    const int bid = blockIdx.x;
    const int v = (bid & 7) * 64 + (bid >> 3);   // XCD-chunked bijective swizzle (512 = 8*64)
    const int nb = v >> 2, kb = v & 3;
    const int n0 = nb * 512;
    const int kw = kb * 256 + w * 32;            // this wave's 32-k strip
    const int loff = l * 8;

    // ---- resident E (A-operand): one frag-major 32-k tile per wave ----
    short8 Eh[16], El[16];
    {
        const unsigned short* bh = ehF + (size_t)(kb * 8 + w) * 8192 + loff;
        const unsigned short* bl = elF + (size_t)(kb * 8 + w) * 8192 + loff;
#pragma unroll
        for (int q = 0; q < 16; ++q) {
            Eh[q] = *reinterpret_cast<const short8*>(bh + q * 512);
            Bl_dummy:;
            El[q] = *reinterpret_cast<const short8*>(bl + q * 512);
        }
    }
    // per-lane e_sq for the 16 k-rows this lane sees (k = kw + crow(r,lh))
    float esql[16];
#pragma unroll
    for (int r = 0; r < 16; ++r)
        esql[r] = esq[kw + (r & 3) + 8 * (r >> 2) + 4 * lh];

    // xsq for the block's 512 n -> LDS (4B DMA per lane)
    __builtin_amdgcn_global_load_lds(
        (const __attribute__((address_space(1))) void*)(xsq + n0 + w * 64 + l),
        (__attribute__((address_space(3))) void*)&xbuf[w * 64], 4, 0, 0);

    asm volatile("s_waitcnt vmcnt(0)" ::: "memory");   // drain E + xbuf
    __builtin_amdgcn_s_barrier();

    // ---- A staging: window s = 64n; chunks: [zh t0 q0-15 | zh t1 | zl t0 | zl t1] ----
#define STAGE(S) do {                                                                   \
    const int _b = (S) & 1;                                                             \
    _Pragma("unroll")                                                                   \
    for (int ci = 0; ci < 8; ++ci) {                                                    \
        int c = 8 * w + ci;                                                             \
        const unsigned short* src = ((c & 32) ? zlF : zhF)                              \
            + (size_t)((n0 >> 5) + (S) * 2 + ((c >> 4) & 1)) * 8192                     \
            + (size_t)(c & 15) * 512 + loff;                                            \
        __builtin_amdgcn_global_load_lds(                                               \
            (const __attribute__((address_space(1))) void*)src,                         \
            (__attribute__((address_space(3))) void*)&abuf[_b][c * 512], 16, 0, 0);     \
    }                                                                                   \
} while (0)

    STAGE(0);

    float rm1 = 3.4e38f, rm2 = 3.4e38f;   // this wave's merged result (window s == w)
    int   ri1 = 0;

    for (int s = 0; s < 8; ++s) {
        const int cur = s & 1;
        // depth-1: my 8 STAGE(s) loads are the only outstanding DMAs.
        // lgkmcnt(0) publishes the previous step's fold writes before the barrier.
        asm volatile("s_waitcnt vmcnt(0) lgkmcnt(0)" ::: "memory");
        __builtin_amdgcn_s_barrier();
        __builtin_amdgcn_sched_barrier(0);
        if (s < 7) STAGE(s + 1);   // into buffer cur^1: consumed last step by everyone

        // deferred merge of window s-1 (parity (s-1)&1), by wave s-1
        if (s >= 1 && w == s - 1) {
            const int pp = (s - 1) & 1;
            float m1 = smp1[pp][0][l], m2 = smp2[pp][0][l];
            int i1 = smi[pp][0][l];
#pragma unroll
            for (int ww = 1; ww < 8; ++ww) {
                float q1 = smp1[pp][ww][l], q2 = smp2[pp][ww][l];
                int qi = smi[pp][ww][l];
                if (q1 < m1)      { m2 = fminf(m1, q2); m1 = q1; i1 = qi; }
                else if (q1 > m1) { m2 = fminf(m2, q1); }
                else              { m2 = m1; }   // ww ascending = k ascending
            }
            rm1 = m1; rm2 = m2; ri1 = i1;
        }

        f32x16 acc0, acc1;
#pragma unroll
        for (int r = 0; r < 16; ++r) { acc0[r] = 0.0f; acc1[r] = 0.0f; }

        __builtin_amdgcn_s_setprio(1);
#pragma unroll
        for (int q = 0; q < 16; ++q) {
            short8 azh0 = *reinterpret_cast<const short8*>(&abuf[cur][(q)      * 512 + loff]);
            short8 azh1 = *reinterpret_cast<const short8*>(&abuf[cur][(16 + q) * 512 + loff]);
            short8 azl0 = *reinterpret_cast<const short8*>(&abuf[cur][(32 + q) * 512 + loff]);
            short8 azl1 = *reinterpret_cast<const short8*>(&abuf[cur][(48 + q) * 512 + loff]);
            acc0 = __builtin_amdgcn_mfma_f32_32x32x16_bf16(Eh[q], azh0, acc0, 0, 0, 0);
            acc1 = __builtin_amdgcn_mfma_f32_32x32x16_bf16(Eh[q], azh1, acc1, 0, 0, 0);
            acc0 = __builtin_amdgcn_mfma_f32_32x32x16_bf16(Eh[q], azl0, acc0, 0, 0, 0);
            acc1 = __builtin_amdgcn_mfma_f32_32x32x16_bf16(Eh[q], azl1, acc1, 0, 0, 0);
            acc0 = __builtin_amdgcn_mfma_f32_32x32x16_bf16(El[q], azh0, acc0, 0, 0, 0);
            acc1 = __builtin_amdgcn_mfma_f32_32x32x16_bf16(El[q], azh1, acc1, 0, 0, 0);
        }
        __builtin_amdgcn_s_setprio(0);

        // fold: lane's col n = lr (per tile); 16 k-rows live in acc registers
#pragma unroll
        for (int i = 0; i < 2; ++i) {
            const f32x16 a = i ? acc1 : acc0;
            const float xs = xbuf[s * 64 + i * 32 + lr];
            float m1 = 3.4e38f, m2 = 3.4e38f;
            int i1 = 0;
#pragma unroll
            for (int r = 0; r < 16; ++r) {            // kg ascending in r
                float sv = (xs + esql[r]) - 2.0f * a[r];
                int kg = kw + (r & 3) + 8 * (r >> 2) + 4 * lh;
                if (sv < m1) { m2 = m1; m1 = sv; i1 = kg; }
                else m2 = fminf(m2, sv);
            }
            // merge lh halves (disjoint k sets for same n)
            float om1 = __shfl_xor(m1, 32, 64);
            float om2 = __shfl_xor(m2, 32, 64);
            int   oi  = __shfl_xor(i1, 32, 64);
            if (om1 < m1)      { m2 = fminf(m1, om2); m1 = om1; i1 = oi; }
            else if (om1 > m1) { m2 = fminf(m2, om1); }
            else               { m2 = m1; i1 = min(i1, oi); }
            if (lh == 0) {
                smp1[s & 1][w][i * 32 + lr] = m1;
                smp2[s & 1][w][i * 32 + lr] = m2;
                smi [s & 1][w][i * 32 + lr] = i1;
            }
        }
        // no second barrier: next step's top lgkmcnt(0)+barrier publishes smp
    }
#undef STAGE

    asm volatile("s_waitcnt lgkmcnt(0)" ::: "memory");
    __builtin_amdgcn_s_barrier();
    if (w == 7) {   // merge window 7 (parity 1)
        float m1 = smp1[1][0][l], m2 = smp2[1][0][l];
        int i1 = smi[1][0][l];
#pragma unroll
        for (int ww = 1; ww < 8; ++ww) {
            float q1 = smp1[1][ww][l], q2 = smp2[1][ww][l];
            int qi = smi[1][ww][l];
            if (q1 < m1)      { m2 = fminf(m1, q2); m1 = q1; i1 = qi; }
            else if (q1 > m1) { m2 = fminf(m2, q1); }
            else              { m2 = m1; }
        }
        rm1 = m1; rm2 = m2; ri1 = i1;
    }

    // wave w owns window s==w: n = n0 + w*64 + l
    {
        size_t p = (size_t)kb * N_VEC + n0 + w * 64 + l;
        pm1[p] = rm1; pm2[p] = rm2; pix[p] = (unsigned short)ri1;
    }
}

// merge + emit fused: unflagged rows finalized here; flagged rows -> refine
__global__ __launch_bounds__(256) void merge_kernel(
    const float* __restrict__ pm1, const float* __restrict__ pm2,
    const unsigned short* __restrict__ pix,
    unsigned* __restrict__ flag_list, unsigned* __restrict__ flag_count,
    float* __restrict__ out_idx, unsigned* __restrict__ counts) {
    int n = blockIdx.x * 256 + threadIdx.x;
    float m1 = 3.4e38f, m2 = 3.4e38f;
    int i1 = 0;
    for (int kb = 0; kb < 4; ++kb) {
        size_t p = (size_t)kb * N_VEC + n;
        float a1 = pm1[p], a2 = pm2[p];
        int ai = (int)pix[p];
        if (a1 < m1)      { m2 = fminf(m1, a2); m1 = a1; i1 = ai; }
        else if (a1 > m1) { m2 = fminf(m2, a1); }
        else              { m2 = m1; i1 = min(i1, ai); }
    }
    if (m2 - m1 <= T_GAP) {
        unsigned pos = atomicAdd(flag_count, 1u);
        flag_list[pos] = (unsigned)n;
    } else {
        out_idx[n] = (float)i1;
        atomicAdd(&counts[i1], 1u);
    }
}

// ---------- exact-chain refine of flagged rows (8 rows/group) ----------

__global__ __launch_bounds__(256) void refine_kernel(
    const float* __restrict__ z, const float* __restrict__ embT,
    const float* __restrict__ esq, const float* __restrict__ xsq,
    const unsigned* __restrict__ flag_list, const unsigned* __restrict__ flag_count,
    float* __restrict__ out_idx, unsigned* __restrict__ counts) {
#pragma clang fp contract(off)
    __shared__ float zrow[8][256];
    __shared__ int nrow[8];
    __shared__ unsigned long long red[8][4];
    const int tid = threadIdx.x;
    const unsigned cnt = *flag_count;
    const unsigned groups = (cnt + 7) >> 3;
    const int kbase = tid * 4;
    for (unsigned g = blockIdx.x; g < groups; g += gridDim.x) {
        __syncthreads();
        if (tid < 8) nrow[tid] = (g * 8 + tid < cnt) ? (int)flag_list[g * 8 + tid] : -1;
        __syncthreads();
        for (int r = 0; r < 8; ++r) {
            int n = nrow[r];
            if (n >= 0) {
                int b = n >> 14, s = n & 16383;
                zrow[r][tid] = z[((size_t)b << 22) + ((size_t)tid << 14) + s];
            }
        }
        __syncthreads();
        float acc[8][4];
#pragma unroll
        for (int r = 0; r < 8; ++r)
#pragma unroll
            for (int j = 0; j < 4; ++j) acc[r][j] = 0.0f;
        for (int c4 = 0; c4 < 64; ++c4) {
            float4 ek[4];
#pragma unroll
            for (int x = 0; x < 4; ++x)
                ek[x] = *reinterpret_cast<const float4*>(embT + (size_t)(c4 * 4 + x) * K_CODES + kbase);
#pragma unroll
            for (int r = 0; r < 8; ++r) {
                float4 zv = *reinterpret_cast<const float4*>(&zrow[r][c4 * 4]);
                float a;
                a = acc[r][0];
                a = fmaf(zv.x, ek[0].x, a); a = fmaf(zv.y, ek[1].x, a);
                a = fmaf(zv.z, ek[2].x, a); a = fmaf(zv.w, ek[3].x, a);
                acc[r][0] = a;
                a = acc[r][1];
                a = fmaf(zv.x, ek[0].y, a); a = fmaf(zv.y, ek[1].y, a);
                a = fmaf(zv.z, ek[2].y, a); a = fmaf(zv.w, ek[3].y, a);
                acc[r][1] = a;
                a = acc[r][2];
                a = fmaf(zv.x, ek[0].z, a); a = fmaf(zv.y, ek[1].z, a);
                a = fmaf(zv.z, ek[2].z, a); a = fmaf(zv.w, ek[3].z, a);
                acc[r][2] = a;
                a = acc[r][3];
                a = fmaf(zv.x, ek[0].w, a); a = fmaf(zv.y, ek[1].w, a);
                a = fmaf(zv.z, ek[2].w, a); a = fmaf(zv.w, ek[3].w, a);
                acc[r][3] = a;
            }
        }
        float esql[4];
#pragma unroll
        for (int j = 0; j < 4; ++j) esql[j] = esq[kbase + j];
#pragma unroll
        for (int r = 0; r < 8; ++r) {
            int n = nrow[r];
            float xs = (n >= 0) ? xsq[n] : 0.0f;
            float m = 3.4e38f;
            int mi = 0;
#pragma unroll
            for (int j = 0; j < 4; ++j) {
                float t1 = xs + esql[j];
                float d = t1 - 2.0f * acc[r][j];
                if (d < m) { m = d; mi = kbase + j; }
            }
            unsigned long long p = ((unsigned long long)__float_as_uint(m) << 32) | (unsigned)mi;
            for (int off = 32; off >= 1; off >>= 1) {
                unsigned long long o = __shfl_xor(p, off, 64);
                p = (o < p) ? o : p;
            }
            if ((tid & 63) == 0) red[r][tid >> 6] = p;
        }
        __syncthreads();
        if (tid < 8 && nrow[tid] >= 0) {
            unsigned long long p = red[tid][0];
#pragma unroll
            for (int ww = 1; ww < 4; ++ww) { unsigned long long o = red[tid][ww]; p = (o < p) ? o : p; }
            int idx = (int)(p & 0xFFFFFFFFull);
            out_idx[nrow[tid]] = (float)idx;
            atomicAdd(&counts[idx], 1u);
        }
    }
}

// ---------- gather + losses (validated) ----------

__global__ __launch_bounds__(256) void gather_kernel(
    const float* __restrict__ z, const float* __restrict__ embT,
    const float* __restrict__ out_idx, float* __restrict__ out,
    double* __restrict__ loss_acc) {
    const int tid = threadIdx.x;
    const int ct = blockIdx.x & 3;
    const int st = (blockIdx.x >> 2) & 15;
    const int b  = blockIdx.x >> 6;
    const int s0 = st * 1024;
    const int c0 = ct * 64;

    int idx[4];
#pragma unroll
    for (int q = 0; q < 4; ++q)
        idx[q] = (int)out_idx[(b << 14) + s0 + 4 * tid + q];

    const float* zb = z + ((size_t)b << 22) + s0 + 4 * tid;
    float* ob = out + ((size_t)b << 22) + s0 + 4 * tid;

    double local = 0.0;
    for (int c = 0; c < 64; ++c) {
        const int cg = c0 + c;
        const float* er = embT + (size_t)cg * K_CODES;
        float4 zv = *reinterpret_cast<const float4*>(zb + ((size_t)cg << 14));
        float4 ov;
        float d0 = er[idx[0]] - zv.x;
        float d1 = er[idx[1]] - zv.y;
        float d2 = er[idx[2]] - zv.z;
        float d3 = er[idx[3]] - zv.w;
        ov.x = zv.x + d0; ov.y = zv.y + d1; ov.z = zv.z + d2; ov.w = zv.w + d3;
        *reinterpret_cast<float4*>(ob + ((size_t)cg << 14)) = ov;
        local += (double)d0 * d0 + (double)d1 * d1 + (double)d2 * d2 + (double)d3 * d3;
    }
    for (int off = 32; off >= 1; off >>= 1) local += __shfl_down(local, off, 64);
    __shared__ double redd[4];
    if ((tid & 63) == 0) redd[tid >> 6] = local;
    __syncthreads();
    if (tid == 0) atomicAdd(loss_acc, redd[0] + redd[1] + redd[2] + redd[3]);
}

__global__ void finalize_kernel(const unsigned* __restrict__ counts,
                                const double* __restrict__ loss_acc,
                                float* __restrict__ out) {
    int tid = threadIdx.x;
    double s = 0.0;
    for (int k = tid; k < K_CODES; k += 256) {
        float avg = (float)counts[k] / 65536.0f;
        float t = avg * logf(avg + 1e-10f);
        s += (double)t;
    }
    for (int off = 32; off >= 1; off >>= 1) s += __shfl_down(s, off, 64);
    __shared__ double red[4];
    if ((tid & 63) == 0) red[tid >> 6] = s;
    __syncthreads();
    if (tid == 0) {
        double tot = red[0] + red[1] + red[2] + red[3];
        out[OUT_PP_OFF]   = expf((float)(-tot));
        out[OUT_LOSS_OFF] = 1.25f * (float)(loss_acc[0] / 16777216.0);
    }
}

extern "C" void kernel_launch(void* const* d_in, const int* in_sizes, int n_in,
                              void* d_out, int out_size, void* d_ws, size_t ws_size,
                              hipStream_t stream) {
    const float* z   = (const float*)d_in[0];
    const float* emb = (const float*)d_in[1];
    float* out = (float*)d_out;
    char* ws = (char*)d_ws;

    unsigned short* ehF = (unsigned short*)(ws + WS_EH);
    unsigned short* elF = (unsigned short*)(ws + WS_EL);
    float*    esq       = (float*)(ws + WS_ESQ);
    float*    xsq       = (float*)(ws + WS_XSQ);
    unsigned* counts    = (unsigned*)(ws + WS_CNT);
    double*   loss_acc  = (double*)(ws + WS_LOSS);
    unsigned* flag_cnt  = (unsigned*)(ws + WS_FLC);
    unsigned* flist     = (unsigned*)(ws + WS_FLIST);
    float*    pm1       = (float*)(ws + WS_PM1);
    float*    pm2       = (float*)(ws + WS_PM2);
    unsigned short* pix = (unsigned short*)(ws + WS_PIX);
    float*    embT      = (float*)(ws + WS_EMBT);

    unsigned short* zhF = (unsigned short*)out;                // [0, 33.5 MB)
    unsigned short* zlF = (unsigned short*)(out + 8388608);    // [33.5, 67 MB)
    float* out_idx = out + OUT_IDX_OFF;

    hipMemsetAsync(ws + WS_CNT, 0, 4108, stream);   // counts + loss + flag_count

    convert_z_kernel<<<1024, 256, 0, stream>>>(z, zhF, zlF, xsq);
    convert_e_kernel<<<128, 256, 0, stream>>>(emb, ehF, elF, esq);
    screen_kernel<<<512, 512, 0, stream>>>(zhF, zlF, ehF, elF, esq, xsq, pm1, pm2, pix);
    merge_kernel<<<256, 256, 0, stream>>>(pm1, pm2, pix, flist, flag_cnt, out_idx, counts);
    transpose_kernel<<<dim3(16, 4), 256, 0, stream>>>(emb, embT);   // embT overlays pm1
    refine_kernel<<<1024, 256, 0, stream>>>(z, embT, esq, xsq, flist, flag_cnt, out_idx, counts);
    gather_kernel<<<256, 256, 0, stream>>>(z, embT, out_idx, out, loss_acc);
    finalize_kernel<<<1, 256, 0, stream>>>(counts, loss_acc, out);
}